// Round 9
// baseline (1019.363 us; speedup 1.0000x reference)
//
#include <hip/hip_runtime.h>
#include <math.h>

// Problem constants
#define NB  262144   // batch
#define SD  128      // STATE_DIM
#define HID 256      // HIDDEN
#define AD  8        // ACTION_DIM

typedef float v2f __attribute__((ext_vector_type(2)));

// d_ws layout (floats)
#define W1T_OFF 0                       // [SD][HID]   W1T[k*HID+j] = W1[j*SD+k]
#define W2T_OFF (SD*HID)                // [HID][HID]  32768
#define W3P_OFF (W2T_OFF + HID*HID)     // [HID][AD] float2 pairs (u,s): 98304, 4096 floats
#define B1_OFF  (W3P_OFF + HID*2*AD)    // 102400
#define B2_OFF  (B1_OFF + HID)          // 102656
#define B3P_OFF (B2_OFF + HID)          // 102912, [AD] float2 pairs
#define WS_FLOATS (B3P_OFF + 2*AD)      // 102928 floats = 411,712 bytes

__global__ __launch_bounds__(256) void prep_weights(
    const float* __restrict__ W1, const float* __restrict__ b1,
    const float* __restrict__ W2, const float* __restrict__ b2,
    const float* __restrict__ W3, const float* __restrict__ b3,
    float* __restrict__ ws) {
  int stride = gridDim.x * blockDim.x;
  for (int i = blockIdx.x * blockDim.x + threadIdx.x; i < WS_FLOATS; i += stride) {
    float v;
    if (i < W2T_OFF) {                       // W1T
      int k = i >> 8, j = i & 255;
      v = W1[j * SD + k];
    } else if (i < W3P_OFF) {                // W2T
      int t = i - W2T_OFF;
      int k = t >> 8, j = t & 255;
      v = W2[j * HID + k];
    } else if (i < B1_OFF) {                 // W3P[k][a] = (W3[a][k], W3[a+8][k])
      int t = i - W3P_OFF;
      int k = t >> 4, a = (t >> 1) & 7, h = t & 1;
      v = W3[(a + 8 * h) * HID + k];
    } else if (i < B2_OFF) {
      v = b1[i - B1_OFF];
    } else if (i < B3P_OFF) {
      v = b2[i - B2_OFF];
    } else {                                 // B3P[a] = (b3[a], b3[a+8])
      int t = i - B3P_OFF;
      v = b3[(t >> 1) + 8 * (t & 1)];
    }
    ws[i] = v;
  }
}

// R13 theory: the immovable ~320 us stall is VMEM TRANSACTION pressure from
// per-wave weight streaming. Evidence: R9 halved weight BYTES but kept
// transaction count constant -> no gain; W2T (256 KB) thrashes the 32 KB L1,
// so every wave re-fetches from L2 (~32 transactions/k-iter/CU vs ~1/cyc TA
// port). R12 (readlane) raised VALU busy 60->74% with dur 900: broadcast via
// VALU is a worse trade. Fix: fetch weights ONCE PER BLOCK. 256-thr/4-wave
// blocks (32 rows); per 16-k-row chunk, stage 16 KB of W into LDS (coalesced
// float4s), barrier, then per-lane ds_read_b128 slices (contiguous 1 KB/wave,
// conflict-free m97 pattern -- NOT the R9/R11 broadcasts). Weight
// transactions drop 4x; fmac k-order bit-identical. h1/h2 stay in
// wave-private s_h rows (XOR float4-group layout, as R8). LDS 32+16=48 KB ->
// 3 blocks/CU.
__global__ __launch_bounds__(256, 3) void actor_fused(
    const float* __restrict__ state, const float* __restrict__ eps,
    const float* __restrict__ ws, int* __restrict__ out) {
  __shared__ float s_h[32][256];   // 32 KiB: h rows, 8 per wave (wave-private)
  __shared__ float s_w[16][256];   // 16 KiB: staged 16-k-row weight chunk

  const int tid  = threadIdx.x;
  const int lane = tid & 63;
  const int wvu  = __builtin_amdgcn_readfirstlane(tid >> 6);  // 0..3, uniform
  const long wrow = (long)blockIdx.x * 32 + wvu * 8;          // wave's first row

  const v2f* __restrict__ W3P = (const v2f*)(ws + W3P_OFF);   // [HID][8]

  const float4* __restrict__ s_w4r = (const float4*)&s_w[0][0];
  float4*       __restrict__ s_w4w = (float4*)&s_w[0][0];

  const float* __restrict__ xbase = state + wrow * SD;   // wave-uniform pointer

  // ---- layer 1: h1 = relu(x @ W1^T + b1), K = 128. 8 chunk-phases of 16 k.
  float acc[8][4];
  #pragma unroll
  for (int r = 0; r < 8; ++r)
    #pragma unroll
    for (int c = 0; c < 4; ++c) acc[r][c] = 0.0f;

  #pragma unroll 1
  for (int kc = 0; kc < SD; kc += 16) {
    // stage W1T rows kc..kc+15 (16 KB = 1024 float4): 4 float4/thread, coalesced
    {
      const float4* __restrict__ g4 = (const float4*)(ws + W1T_OFF + kc * HID);
      #pragma unroll
      for (int i = 0; i < 4; ++i) {
        const int f = i * 256 + tid;
        s_w4w[f] = g4[f];
      }
    }
    __syncthreads();
    #pragma unroll
    for (int kk = 0; kk < 16; kk += 4) {
      const int k0 = kc + kk;
      float4 w[4];
      #pragma unroll
      for (int j = 0; j < 4; ++j) w[j] = s_w4r[(kk + j) * 64 + lane];  // 1KB/wave, conflict-free
      float4 xv[8];
      #pragma unroll
      for (int r = 0; r < 8; ++r)                       // uniform address: one line
        xv[r] = *(const float4*)(xbase + r * SD + k0);  // serves the whole wave
      #pragma unroll
      for (int j = 0; j < 4; ++j) {
        #pragma unroll
        for (int r = 0; r < 8; ++r) {
          float x = (j == 0) ? xv[r].x : (j == 1) ? xv[r].y
                  : (j == 2) ? xv[r].z : xv[r].w;
          acc[r][0] = fmaf(x, w[j].x, acc[r][0]);
          acc[r][1] = fmaf(x, w[j].y, acc[r][1]);
          acc[r][2] = fmaf(x, w[j].z, acc[r][2]);
          acc[r][3] = fmaf(x, w[j].w, acc[r][3]);
        }
      }
    }
    __syncthreads();   // protect s_w until every wave finished this chunk
  }

  // bias + relu -> wave-private LDS rows; float4-group g stored at (g ^ r)
  {
    float4 bb = ((const float4*)(ws + B1_OFF))[lane];
    #pragma unroll
    for (int r = 0; r < 8; ++r) {
      float4 hv;
      hv.x = acc[r][0] + bb.x; hv.y = acc[r][1] + bb.y;
      hv.z = acc[r][2] + bb.z; hv.w = acc[r][3] + bb.w;
      hv.x = hv.x > 0.0f ? hv.x : 0.0f;
      hv.y = hv.y > 0.0f ? hv.y : 0.0f;
      hv.z = hv.z > 0.0f ? hv.z : 0.0f;
      hv.w = hv.w > 0.0f ? hv.w : 0.0f;
      *(float4*)&s_h[wvu * 8 + r][(lane ^ r) << 2] = hv;
    }
  }

  // ---- layer 2: h2 = relu(h1 @ W2^T + b2), K = 256. 16 chunk-phases of 16 k.
  #pragma unroll
  for (int r = 0; r < 8; ++r)
    #pragma unroll
    for (int c = 0; c < 4; ++c) acc[r][c] = 0.0f;

  #pragma unroll 1
  for (int kc = 0; kc < HID; kc += 16) {
    {
      const float4* __restrict__ g4 = (const float4*)(ws + W2T_OFF + kc * HID);
      #pragma unroll
      for (int i = 0; i < 4; ++i) {
        const int f = i * 256 + tid;
        s_w4w[f] = g4[f];
      }
    }
    __syncthreads();
    #pragma unroll
    for (int kk = 0; kk < 16; kk += 4) {
      const int k0 = kc + kk;
      float4 w[4];
      #pragma unroll
      for (int j = 0; j < 4; ++j) w[j] = s_w4r[(kk + j) * 64 + lane];
      float4 xv[8];
      #pragma unroll
      for (int r = 0; r < 8; ++r)                       // wave-private uniform LDS
        xv[r] = *(const float4*)&s_h[wvu * 8 + r][(((k0 >> 2) ^ r) << 2)];  // broadcast
      #pragma unroll
      for (int j = 0; j < 4; ++j) {
        #pragma unroll
        for (int r = 0; r < 8; ++r) {
          float x = (j == 0) ? xv[r].x : (j == 1) ? xv[r].y
                  : (j == 2) ? xv[r].z : xv[r].w;
          acc[r][0] = fmaf(x, w[j].x, acc[r][0]);
          acc[r][1] = fmaf(x, w[j].y, acc[r][1]);
          acc[r][2] = fmaf(x, w[j].z, acc[r][2]);
          acc[r][3] = fmaf(x, w[j].w, acc[r][3]);
        }
      }
    }
    __syncthreads();
  }

  // bias + relu -> h2 into the SAME wave-private LDS rows
  {
    float4 bb = ((const float4*)(ws + B2_OFF))[lane];
    #pragma unroll
    for (int r = 0; r < 8; ++r) {
      float4 hv;
      hv.x = acc[r][0] + bb.x; hv.y = acc[r][1] + bb.y;
      hv.z = acc[r][2] + bb.z; hv.w = acc[r][3] + bb.w;
      hv.x = hv.x > 0.0f ? hv.x : 0.0f;
      hv.y = hv.y > 0.0f ? hv.y : 0.0f;
      hv.z = hv.z > 0.0f ? hv.z : 0.0f;
      hv.w = hv.w > 0.0f ? hv.w : 0.0f;
      *(float4*)&s_h[wvu * 8 + r][(lane ^ r) << 2] = hv;
    }
  }

  // ---- layer 3 (K=256, N=16) + epilogue. Lane -> (row = lane>>3, action = lane&7),
  // both u and s chains serial k-ascending (matches sgemm).
  {
    const int r3 = lane >> 3;
    const int a  = lane & 7;
    const float* __restrict__ h2row = &s_h[wvu * 8 + r3][0];
    float accu = 0.0f, accs = 0.0f;
    #pragma unroll 2
    for (int k0 = 0; k0 < HID; k0 += 4) {
      const int col = ((k0 >> 2) ^ r3) << 2;          // XOR layout; 8 rows -> 8 banks
      v2f ha = *(const v2f*)(h2row + col);            // k0, k0+1 (8-lane broadcast)
      v2f hb = *(const v2f*)(h2row + col + 2);        // k0+2, k0+3
      v2f wp0 = W3P[(k0 + 0) * 8 + a];
      v2f wp1 = W3P[(k0 + 1) * 8 + a];
      v2f wp2 = W3P[(k0 + 2) * 8 + a];
      v2f wp3 = W3P[(k0 + 3) * 8 + a];
      accu = fmaf(ha.x, wp0.x, accu); accs = fmaf(ha.x, wp0.y, accs);
      accu = fmaf(ha.y, wp1.x, accu); accs = fmaf(ha.y, wp1.y, accs);
      accu = fmaf(hb.x, wp2.x, accu); accs = fmaf(hb.x, wp2.y, accs);
      accu = fmaf(hb.y, wp3.x, accu); accs = fmaf(hb.y, wp3.y, accs);
    }
    v2f b3p = ((const v2f*)(ws + B3P_OFF))[a];
    float nu = accu + b3p.x;
    float ns = accs + b3p.y;

    long grow = wrow + r3;
    float sa = fabsf(ns);
    float ev = eps[grow * AD + a];                // coalesced: base + lane
    float t  = __fmul_rn(sa, ev);                 // separately-rounded mul
    float z  = __fadd_rn(nu, t);                  // separately-rounded add
    float e  = (float)exp(-(double)z);            // correctly-rounded expf near boundary
    float d  = __fadd_rn(1.0f, e);
    float act = 1.0f / d;
    float q  = act * 8.0f;                        // exact
    float wq = __fadd_rn(q, 1.0f);
    out[grow * AD + a] = (int)wq;                 // truncation, as astype(int32)
  }
}

extern "C" void kernel_launch(void* const* d_in, const int* in_sizes, int n_in,
                              void* d_out, int out_size, void* d_ws, size_t ws_size,
                              hipStream_t stream) {
  const float* state = (const float*)d_in[0];
  const float* W1    = (const float*)d_in[1];
  const float* b1    = (const float*)d_in[2];
  const float* W2    = (const float*)d_in[3];
  const float* b2    = (const float*)d_in[4];
  const float* W3    = (const float*)d_in[5];
  const float* b3    = (const float*)d_in[6];
  const float* eps   = (const float*)d_in[7];
  int*   out = (int*)d_out;
  float* ws  = (float*)d_ws;   // 411,712 bytes; rebuilt every launch

  hipLaunchKernelGGL(prep_weights, dim3(128), dim3(256), 0, stream,
                     W1, b1, W2, b2, W3, b3, ws);
  hipLaunchKernelGGL(actor_fused, dim3(NB / 32), dim3(256), 0, stream,
                     state, eps, ws, out);
}

// Round 10
// 980.203 us; speedup vs baseline: 1.0400x; 1.0400x over previous
//
#include <hip/hip_runtime.h>
#include <math.h>

// Problem constants
#define NB  262144   // batch
#define SD  128      // STATE_DIM
#define HID 256      // HIDDEN
#define AD  8        // ACTION_DIM

typedef float v2f __attribute__((ext_vector_type(2)));

// d_ws layout (floats)
#define W1T_OFF 0                       // [SD][HID]   W1T[k*HID+j] = W1[j*SD+k]
#define W2T_OFF (SD*HID)                // [HID][HID]  32768
#define W3P_OFF (W2T_OFF + HID*HID)     // [HID][AD] float2 pairs (u,s): 98304, 4096 floats
#define B1_OFF  (W3P_OFF + HID*2*AD)    // 102400
#define B2_OFF  (B1_OFF + HID)          // 102656
#define B3P_OFF (B2_OFF + HID)          // 102912, [AD] float2 pairs
#define WS_FLOATS (B3P_OFF + 2*AD)      // 102928 floats = 411,712 bytes

__global__ __launch_bounds__(256) void prep_weights(
    const float* __restrict__ W1, const float* __restrict__ b1,
    const float* __restrict__ W2, const float* __restrict__ b2,
    const float* __restrict__ W3, const float* __restrict__ b3,
    float* __restrict__ ws) {
  int stride = gridDim.x * blockDim.x;
  for (int i = blockIdx.x * blockDim.x + threadIdx.x; i < WS_FLOATS; i += stride) {
    float v;
    if (i < W2T_OFF) {                       // W1T
      int k = i >> 8, j = i & 255;
      v = W1[j * SD + k];
    } else if (i < W3P_OFF) {                // W2T
      int t = i - W2T_OFF;
      int k = t >> 8, j = t & 255;
      v = W2[j * HID + k];
    } else if (i < B1_OFF) {                 // W3P[k][a] = (W3[a][k], W3[a+8][k])
      int t = i - W3P_OFF;
      int k = t >> 4, a = (t >> 1) & 7, h = t & 1;
      v = W3[(a + 8 * h) * HID + k];
    } else if (i < B2_OFF) {
      v = b1[i - B1_OFF];
    } else if (i < B3P_OFF) {
      v = b2[i - B2_OFF];
    } else {                                 // B3P[a] = (b3[a], b3[a+8])
      int t = i - B3P_OFF;
      v = b3[(t >> 1) + 8 * (t & 1)];
    }
    ws[i] = v;
  }
}

// R14: clean test of the weight-TRANSACTION theory (R13's test was
// contaminated: (256,3) cap 85 < ~120 live -> 110 MB spill + 24 barriers +
// Occ 34%). Evidence for the theory: R9 halved weight BYTES at constant
// transaction count -> no gain; per k-iter each wave issues 4 wave-wide b128
// weight loads = 32 line-requests per 128 fmacs, and W2T (256 KB) thrashes
// the 32 KB L1 so all go to L2. That request/fmac rate is the one invariant
// across R6-R12 -- and dur never moved.
//
// Mechanism: 16 rows/wave (was 8). Same 4 weight loads/k-iter now feed 256
// fmacs -> transaction rate per fmac HALVES. No barriers, no new LDS
// traffic: single-wave 64-thread blocks, s_h[16][256]=16 KB wave-private,
// R8 skeleton with acc[16][4] (64 VGPR) and xv processed 8 rows at a time.
// __launch_bounds__(64,2) -> VGPR cap 128 >= ~124 live, no spill (gate:
// WRITE_SIZE must stay ~8.2 MB). Layer 3 = two 8-row passes.
__global__ __launch_bounds__(64, 2) void actor_fused(
    const float* __restrict__ state, const float* __restrict__ eps,
    const float* __restrict__ ws, int* __restrict__ out) {
  __shared__ float s_h[16][256];   // 16,384 B, wave-private (1 wave/block)

  const int lane = threadIdx.x;              // block == one wave
  const long wrow = (long)blockIdx.x * 16;   // this wave's first row

  const float4* __restrict__ W1T4 = (const float4*)(ws + W1T_OFF);  // [SD][64]
  const float4* __restrict__ W2T4 = (const float4*)(ws + W2T_OFF);  // [HID][64]
  const v2f*    __restrict__ W3P  = (const v2f*)(ws + W3P_OFF);     // [HID][8]

  const float* __restrict__ xbase = state + wrow * SD;   // uniform pointer

  // ---- layer 1: h1 = relu(x @ W1^T + b1), K = 128, 16 rows
  float acc[16][4];
  #pragma unroll
  for (int r = 0; r < 16; ++r)
    #pragma unroll
    for (int c = 0; c < 4; ++c) acc[r][c] = 0.0f;

  #pragma unroll 1
  for (int k0 = 0; k0 < SD; k0 += 4) {
    float4 w[4];
    #pragma unroll
    for (int j = 0; j < 4; ++j) w[j] = W1T4[(k0 + j) * 64 + lane];
    #pragma unroll
    for (int rg = 0; rg < 2; ++rg) {         // 8 rows in flight at a time
      float4 xv[8];
      #pragma unroll
      for (int r = 0; r < 8; ++r)                       // uniform address: one line
        xv[r] = *(const float4*)(xbase + (rg * 8 + r) * SD + k0);
      #pragma unroll
      for (int j = 0; j < 4; ++j) {
        #pragma unroll
        for (int r = 0; r < 8; ++r) {
          const int R = rg * 8 + r;
          float x = (j == 0) ? xv[r].x : (j == 1) ? xv[r].y
                  : (j == 2) ? xv[r].z : xv[r].w;
          acc[R][0] = fmaf(x, w[j].x, acc[R][0]);
          acc[R][1] = fmaf(x, w[j].y, acc[R][1]);
          acc[R][2] = fmaf(x, w[j].z, acc[R][2]);
          acc[R][3] = fmaf(x, w[j].w, acc[R][3]);
        }
      }
    }
  }

  // bias + relu -> wave-private LDS rows; float4-group g stored at (g ^ r)
  {
    float4 bb = ((const float4*)(ws + B1_OFF))[lane];
    #pragma unroll
    for (int r = 0; r < 16; ++r) {
      float4 hv;
      hv.x = acc[r][0] + bb.x; hv.y = acc[r][1] + bb.y;
      hv.z = acc[r][2] + bb.z; hv.w = acc[r][3] + bb.w;
      hv.x = hv.x > 0.0f ? hv.x : 0.0f;
      hv.y = hv.y > 0.0f ? hv.y : 0.0f;
      hv.z = hv.z > 0.0f ? hv.z : 0.0f;
      hv.w = hv.w > 0.0f ? hv.w : 0.0f;
      *(float4*)&s_h[r][(lane ^ r) << 2] = hv;
    }
  }

  // ---- layer 2: h2 = relu(h1 @ W2^T + b2), K = 256, 16 rows
  #pragma unroll
  for (int r = 0; r < 16; ++r)
    #pragma unroll
    for (int c = 0; c < 4; ++c) acc[r][c] = 0.0f;

  #pragma unroll 1
  for (int k0 = 0; k0 < HID; k0 += 4) {
    float4 w[4];
    #pragma unroll
    for (int j = 0; j < 4; ++j) w[j] = W2T4[(k0 + j) * 64 + lane];
    #pragma unroll
    for (int rg = 0; rg < 2; ++rg) {
      float4 xv[8];
      #pragma unroll
      for (int r = 0; r < 8; ++r) {                     // uniform LDS address ->
        const int R = rg * 8 + r;                       // HW broadcast, no conflict
        xv[r] = *(const float4*)&s_h[R][(((k0 >> 2) ^ R) << 2)];
      }
      #pragma unroll
      for (int j = 0; j < 4; ++j) {
        #pragma unroll
        for (int r = 0; r < 8; ++r) {
          const int R = rg * 8 + r;
          float x = (j == 0) ? xv[r].x : (j == 1) ? xv[r].y
                  : (j == 2) ? xv[r].z : xv[r].w;
          acc[R][0] = fmaf(x, w[j].x, acc[R][0]);
          acc[R][1] = fmaf(x, w[j].y, acc[R][1]);
          acc[R][2] = fmaf(x, w[j].z, acc[R][2]);
          acc[R][3] = fmaf(x, w[j].w, acc[R][3]);
        }
      }
    }
  }

  // bias + relu -> h2 into the SAME LDS rows (all h1 reads done, program order)
  {
    float4 bb = ((const float4*)(ws + B2_OFF))[lane];
    #pragma unroll
    for (int r = 0; r < 16; ++r) {
      float4 hv;
      hv.x = acc[r][0] + bb.x; hv.y = acc[r][1] + bb.y;
      hv.z = acc[r][2] + bb.z; hv.w = acc[r][3] + bb.w;
      hv.x = hv.x > 0.0f ? hv.x : 0.0f;
      hv.y = hv.y > 0.0f ? hv.y : 0.0f;
      hv.z = hv.z > 0.0f ? hv.z : 0.0f;
      hv.w = hv.w > 0.0f ? hv.w : 0.0f;
      *(float4*)&s_h[r][(lane ^ r) << 2] = hv;
    }
  }

  // ---- layer 3 (K=256, N=16) + epilogue, two 8-row passes.
  // Pass p: lane -> (row = p*8 + lane>>3, action = lane&7); u and s chains
  // serial k-ascending (matches sgemm).
  #pragma unroll
  for (int p = 0; p < 2; ++p) {
    const int r3 = p * 8 + (lane >> 3);
    const int a  = lane & 7;
    const float* __restrict__ h2row = &s_h[r3][0];
    float accu = 0.0f, accs = 0.0f;
    #pragma unroll 2
    for (int k0 = 0; k0 < HID; k0 += 4) {
      const int col = ((k0 >> 2) ^ r3) << 2;          // XOR layout; 8 rows -> 8 banks
      v2f ha = *(const v2f*)(h2row + col);            // k0, k0+1 (8-lane broadcast)
      v2f hb = *(const v2f*)(h2row + col + 2);        // k0+2, k0+3
      v2f wp0 = W3P[(k0 + 0) * 8 + a];
      v2f wp1 = W3P[(k0 + 1) * 8 + a];
      v2f wp2 = W3P[(k0 + 2) * 8 + a];
      v2f wp3 = W3P[(k0 + 3) * 8 + a];
      accu = fmaf(ha.x, wp0.x, accu); accs = fmaf(ha.x, wp0.y, accs);
      accu = fmaf(ha.y, wp1.x, accu); accs = fmaf(ha.y, wp1.y, accs);
      accu = fmaf(hb.x, wp2.x, accu); accs = fmaf(hb.x, wp2.y, accs);
      accu = fmaf(hb.y, wp3.x, accu); accs = fmaf(hb.y, wp3.y, accs);
    }
    v2f b3p = ((const v2f*)(ws + B3P_OFF))[a];
    float nu = accu + b3p.x;
    float ns = accs + b3p.y;

    long grow = wrow + r3;
    float sa = fabsf(ns);
    float ev = eps[grow * AD + a];                // coalesced within the pass
    float t  = __fmul_rn(sa, ev);                 // separately-rounded mul
    float z  = __fadd_rn(nu, t);                  // separately-rounded add
    float e  = (float)exp(-(double)z);            // correctly-rounded expf near boundary
    float d  = __fadd_rn(1.0f, e);
    float act = 1.0f / d;
    float q  = act * 8.0f;                        // exact
    float wq = __fadd_rn(q, 1.0f);
    out[grow * AD + a] = (int)wq;                 // truncation, as astype(int32)
  }
}

extern "C" void kernel_launch(void* const* d_in, const int* in_sizes, int n_in,
                              void* d_out, int out_size, void* d_ws, size_t ws_size,
                              hipStream_t stream) {
  const float* state = (const float*)d_in[0];
  const float* W1    = (const float*)d_in[1];
  const float* b1    = (const float*)d_in[2];
  const float* W2    = (const float*)d_in[3];
  const float* b2    = (const float*)d_in[4];
  const float* W3    = (const float*)d_in[5];
  const float* b3    = (const float*)d_in[6];
  const float* eps   = (const float*)d_in[7];
  int*   out = (int*)d_out;
  float* ws  = (float*)d_ws;   // 411,712 bytes; rebuilt every launch

  hipLaunchKernelGGL(prep_weights, dim3(128), dim3(256), 0, stream,
                     W1, b1, W2, b2, W3, b3, ws);
  hipLaunchKernelGGL(actor_fused, dim3(NB / 16), dim3(64), 0, stream,
                     state, eps, ws, out);
}